// Round 6
// baseline (998.112 us; speedup 1.0000x reference)
//
#include <hip/hip_runtime.h>
#include <math.h>

#define BATCH  128
#define NENT   256
#define INDIM  256
#define HID    512
#define NHEAD  8
#define NAGENT 64
#define SCALE  0.04419417382415922f   // 1/sqrt(512)

// Packed split-bf16 layout: row-major rows of k-blocks; each 32-k block is
// 128 B = [32 x u16 hi | 32 x u16 lo] -> one full cache line per frag pair.
// h_p:  [32768][16 blk][64]  (64 MB)   Mt_p: [8][512][16 blk][64] (8 MB)
// Wt_p: [512][8 blk][64] (512 KB, transient)

typedef unsigned short u16;
typedef unsigned int   u32;

typedef __bf16 bf16x8  __attribute__((ext_vector_type(8)));
typedef float  floatx4 __attribute__((ext_vector_type(4)));
typedef u32    u32x4   __attribute__((ext_vector_type(4)));
typedef u32    u32x2   __attribute__((ext_vector_type(2)));

union Frag {
    u32x4 s;
    struct { u32x2 lo, hi; } p;
    bf16x8 v;
};

__device__ __forceinline__ u16 f2bf(float x) {
    u32 u = __float_as_uint(x);
    return (u16)((u + 0x7FFFu + ((u >> 16) & 1u)) >> 16);
}
__device__ __forceinline__ float bf2f(u16 b) {
    return __uint_as_float(((u32)b) << 16);
}
__device__ __forceinline__ void split4(const float4& r, ushort4& hh, ushort4& hl) {
    hh.x = f2bf(r.x); hl.x = f2bf(r.x - bf2f(hh.x));
    hh.y = f2bf(r.y); hl.y = f2bf(r.y - bf2f(hh.y));
    hh.z = f2bf(r.z); hl.z = f2bf(r.z - bf2f(hh.z));
    hh.w = f2bf(r.w); hl.w = f2bf(r.w - bf2f(hh.w));
}
__device__ __forceinline__ floatx4 mm(const Frag& a, const Frag& b, floatx4 c) {
    return __builtin_amdgcn_mfma_f32_16x16x32_bf16(a.v, b.v, c, 0, 0, 0);
}
#define SB() __builtin_amdgcn_sched_barrier(0)

// -----------------------------------------------------------------------------
// K0: Wt_p[d][k] = packed split(W_enc[k][d])  (transpose), 512 x 256
// -----------------------------------------------------------------------------
__global__ __launch_bounds__(256) void wenc_t_kernel(const float* __restrict__ W,
                                                     u16* __restrict__ Wt_p) {
    __shared__ float tile[64][68];
    const int bid = blockIdx.x;          // 4 k-tiles x 8 d-tiles
    const int k0 = (bid & 3) * 64;
    const int d0 = (bid >> 2) * 64;
    const int t = threadIdx.x;
    const int ki = t >> 2, dc = (t & 3) * 16;
    #pragma unroll
    for (int c = 0; c < 4; ++c)
        *(float4*)&tile[ki][dc + c * 4] =
            *(const float4*)(W + (size_t)(k0 + ki) * HID + d0 + dc + c * 4);
    __syncthreads();
    const int dr = t >> 2, kc = (t & 3) * 16;
    #pragma unroll
    for (int c = 0; c < 4; ++c) {
        float4 v = make_float4(tile[kc + c * 4 + 0][dr], tile[kc + c * 4 + 1][dr],
                               tile[kc + c * 4 + 2][dr], tile[kc + c * 4 + 3][dr]);
        ushort4 hh, hl; split4(v, hh, hl);
        const int kk = k0 + kc + c * 4;
        size_t o = (size_t)(d0 + dr) * 512 + (size_t)(kk >> 5) * 64 + (kk & 31);
        *(ushort4*)(Wt_p + o) = hh;
        *(ushort4*)(Wt_p + o + 32) = hl;
    }
}

// -----------------------------------------------------------------------------
// K1: h = leaky_relu(x) @ W_enc + b_enc via split-bf16 3-pass MFMA -> h_p packed
// -----------------------------------------------------------------------------
__global__ __launch_bounds__(256) void enc_kernel(const float* __restrict__ x,
                                                  const u16* __restrict__ Wt_p,
                                                  const float* __restrict__ bias,
                                                  u16* __restrict__ h_p) {
    __shared__ u16 Ah[32][264];
    __shared__ u16 Al[32][264];
    const int r0 = blockIdx.x * 32;
    const int t  = threadIdx.x;
    {
        const int row = t >> 3;
        const float* xr = x + (size_t)(r0 + row) * INDIM;
        #pragma unroll
        for (int j = 0; j < 8; ++j) {
            const int k0 = ((t & 7) + j * 8) * 4;
            float4 v = *(const float4*)(xr + k0);
            v.x = v.x > 0.f ? v.x : 0.01f * v.x;
            v.y = v.y > 0.f ? v.y : 0.01f * v.y;
            v.z = v.z > 0.f ? v.z : 0.01f * v.z;
            v.w = v.w > 0.f ? v.w : 0.01f * v.w;
            ushort4 hh, hl; split4(v, hh, hl);
            *(ushort4*)&Ah[row][k0] = hh;
            *(ushort4*)&Al[row][k0] = hl;
        }
    }
    __syncthreads();

    const int wid = t >> 6, lane = t & 63, l15 = lane & 15, quad = lane >> 4;
    const int mbase = (wid & 1) * 16;
    const int nbase = (wid >> 1) * 256;
    const floatx4 z4 = {0.f, 0.f, 0.f, 0.f};
    floatx4 acc[16];
    #pragma unroll
    for (int i = 0; i < 16; ++i) acc[i] = z4;

    for (int ks = 0; ks < 8; ++ks) {
        const int k = ks * 32 + quad * 8;
        Frag Afh, Afl;
        Afh.s = *(const u32x4*)&Ah[mbase + l15][k];
        Afl.s = *(const u32x4*)&Al[mbase + l15][k];
        #pragma unroll
        for (int nt = 0; nt < 16; ++nt) {
            const int d = nbase + nt * 16 + l15;
            const size_t wo = (size_t)d * 512 + (size_t)ks * 64 + quad * 8;
            Frag Bh, Bl;
            Bh.s = *(const u32x4*)(Wt_p + wo);
            Bl.s = *(const u32x4*)(Wt_p + wo + 32);
            floatx4 c = acc[nt];
            c = __builtin_amdgcn_mfma_f32_16x16x32_bf16(Afh.v, Bh.v, c, 0, 0, 0);
            c = __builtin_amdgcn_mfma_f32_16x16x32_bf16(Afh.v, Bl.v, c, 0, 0, 0);
            c = __builtin_amdgcn_mfma_f32_16x16x32_bf16(Afl.v, Bh.v, c, 0, 0, 0);
            acc[nt] = c;
        }
    }
    #pragma unroll
    for (int nt = 0; nt < 16; ++nt) {
        const int d = nbase + nt * 16 + l15;
        const float bv = bias[d];
        #pragma unroll
        for (int r = 0; r < 4; ++r) {
            const float v = acc[nt][r] + bv;
            const u16 hi = f2bf(v);
            const u16 lo = f2bf(v - bf2f(hi));
            const size_t o = (size_t)(r0 + mbase + quad * 4 + r) * 1024
                           + (size_t)(d >> 5) * 64 + (d & 31);
            h_p[o]      = hi;
            h_p[o + 32] = lo;
        }
    }
}

// -----------------------------------------------------------------------------
// K1b: hT[b][d][e] = hi(h[b*256+e][d])  (64x64 u16 tile transpose, from packed)
// -----------------------------------------------------------------------------
__global__ __launch_bounds__(256) void ht_kernel(const u16* __restrict__ h_p,
                                                 u16* __restrict__ hT) {
    __shared__ u16 tile[64][72];
    const int bid = blockIdx.x;               // 8 dt x 4 et x 128 b
    const int dt = bid & 7;
    const int et = (bid >> 3) & 3;
    const int b  = bid >> 5;
    const int t  = threadIdx.x;
    const int r  = t >> 2, cs = (t & 3) * 16;
    const int dg = dt * 64 + cs;
    const u16* src = h_p + (size_t)(b * 256 + et * 64 + r) * 1024
                   + (size_t)(dg >> 5) * 64 + (dg & 31);
    *(ushort4*)&tile[r][cs + 0]  = *(const ushort4*)(src + 0);
    *(ushort4*)&tile[r][cs + 4]  = *(const ushort4*)(src + 4);
    *(ushort4*)&tile[r][cs + 8]  = *(const ushort4*)(src + 8);
    *(ushort4*)&tile[r][cs + 12] = *(const ushort4*)(src + 12);
    __syncthreads();
    const int d = t >> 2, es = (t & 3) * 16;
    u16* dst = hT + (size_t)b * 131072 + (size_t)(dt * 64 + d) * 256 + et * 64 + es;
    #pragma unroll
    for (int c = 0; c < 4; ++c) {
        ushort4 v = make_ushort4(tile[es + c * 4 + 0][d], tile[es + c * 4 + 1][d],
                                 tile[es + c * 4 + 2][d], tile[es + c * 4 + 3][d]);
        *(ushort4*)(dst + c * 4) = v;
    }
}

// -----------------------------------------------------------------------------
// K2: Mt_p[n][j][i] = packed split(SCALE * dot(WQ[n][i,:], WK[n][j,:]))
// -----------------------------------------------------------------------------
__global__ __launch_bounds__(256) void wqk_kernel(const float* __restrict__ WQ,
                                                  const float* __restrict__ WK,
                                                  u16* __restrict__ Mt_p) {
    __shared__ u16 Ah[64][72], Al[64][72], Bh[64][72], Bl[64][72];
    const int bid = blockIdx.x;
    const int jt = (bid & 7) * 64;
    const int it = ((bid >> 3) & 7) * 64;
    const int n  = bid >> 6;
    const float* qp = WQ + (size_t)n * 262144;
    const float* kp = WK + (size_t)n * 262144;
    const int t = threadIdx.x;
    const int wid = t >> 6, lane = t & 63, l15 = lane & 15, quad = lane >> 4;
    const int srow = t >> 2, sc = (t & 3) * 16;

    const floatx4 z4 = {0.f, 0.f, 0.f, 0.f};
    floatx4 acc[4];
    #pragma unroll
    for (int i = 0; i < 4; ++i) acc[i] = z4;

    for (int kc = 0; kc < HID; kc += 64) {
        #pragma unroll
        for (int f = 0; f < 4; ++f) {
            float4 va = *(const float4*)(kp + (size_t)(jt + srow) * HID + kc + sc + f * 4);
            ushort4 hh, hl; split4(va, hh, hl);
            *(ushort4*)&Ah[srow][sc + f * 4] = hh;
            *(ushort4*)&Al[srow][sc + f * 4] = hl;
            float4 vb = *(const float4*)(qp + (size_t)(it + srow) * HID + kc + sc + f * 4);
            split4(vb, hh, hl);
            *(ushort4*)&Bh[srow][sc + f * 4] = hh;
            *(ushort4*)&Bl[srow][sc + f * 4] = hl;
        }
        __syncthreads();
        #pragma unroll
        for (int ks = 0; ks < 2; ++ks) {
            const int k = ks * 32 + quad * 8;
            Frag Afh, Afl;
            Afh.s = *(const u32x4*)&Ah[wid * 16 + l15][k];
            Afl.s = *(const u32x4*)&Al[wid * 16 + l15][k];
            #pragma unroll
            for (int nt = 0; nt < 4; ++nt) {
                Frag Bfh, Bfl;
                Bfh.s = *(const u32x4*)&Bh[nt * 16 + l15][k];
                Bfl.s = *(const u32x4*)&Bl[nt * 16 + l15][k];
                floatx4 c = acc[nt];
                c = __builtin_amdgcn_mfma_f32_16x16x32_bf16(Afh.v, Bfh.v, c, 0, 0, 0);
                c = __builtin_amdgcn_mfma_f32_16x16x32_bf16(Afh.v, Bfl.v, c, 0, 0, 0);
                c = __builtin_amdgcn_mfma_f32_16x16x32_bf16(Afl.v, Bfh.v, c, 0, 0, 0);
                acc[nt] = c;
            }
        }
        __syncthreads();
    }
    #pragma unroll
    for (int nt = 0; nt < 4; ++nt)
        #pragma unroll
        for (int r = 0; r < 4; ++r) {
            const float v = acc[nt][r] * SCALE;
            const u16 hi = f2bf(v);
            const u16 lo = f2bf(v - bf2f(hi));
            const int j = jt + wid * 16 + quad * 4 + r;
            const int i = it + nt * 16 + l15;
            const size_t o = (size_t)n * 524288 + (size_t)j * 1024
                           + (size_t)(i >> 5) * 64 + (i & 31);
            Mt_p[o]      = hi;
            Mt_p[o + 32] = lo;
        }
}

// -----------------------------------------------------------------------------
// K3: WVt[n][dout][din] = bf16(WV[n][din][dout])
// -----------------------------------------------------------------------------
__global__ __launch_bounds__(256) void wvt_kernel(const float* __restrict__ WV,
                                                  u16* __restrict__ WVt) {
    __shared__ float tile[64][68];
    const int bid = blockIdx.x;
    const int i0 = (bid & 7) * 64;
    const int o0 = ((bid >> 3) & 7) * 64;
    const int n  = bid >> 6;
    const float* src = WV + (size_t)n * 262144;
    const int t  = threadIdx.x;
    const int di = t >> 2;
    const int dc = (t & 3) * 16;
    #pragma unroll
    for (int c = 0; c < 4; ++c)
        *(float4*)&tile[di][dc + c * 4] =
            *(const float4*)(src + (size_t)(i0 + di) * HID + o0 + dc + c * 4);
    __syncthreads();
    const int dr = t >> 2;
    const int ic = (t & 3) * 16;
    size_t o = (size_t)n * 262144 + (size_t)(o0 + dr) * HID + i0 + ic;
    #pragma unroll
    for (int c = 0; c < 4; ++c) {
        ushort4 v = make_ushort4(f2bf(tile[ic + c * 4 + 0][dr]), f2bf(tile[ic + c * 4 + 1][dr]),
                                 f2bf(tile[ic + c * 4 + 2][dr]), f2bf(tile[ic + c * 4 + 3][dr]));
        *(ushort4*)(WVt + o + c * 4) = v;
    }
}

// -----------------------------------------------------------------------------
// K4: fused MFMA attention, sched_barrier(0)-ENFORCED register pipelining.
// R5 lesson: named double-buffers alone get collapsed by regalloc (VGPR stayed
// 80, schedule re-serialized). Fix: LD(next batch); sched_barrier(0); MFMA(cur)
// — SB(0) forbids sinking the loads, so buffers must materialize and the
// auto-waitcnt before each MFMA cluster becomes a counted vmcnt with the next
// batch in flight (T4 semantics). Phase A B-stream lead deepened to 2 batches
// (B0..B3 rotation = 12-MFMA cover; x3 waves TLP ~ 200-350 cyc).
// Tripwires: VGPR_Count must RISE (else compiler defeated SB);
// WRITE_SIZE must stay exactly 131072 KB (else spilled, R1-R3 lesson).
// Tail prefetch indices masked (&7/&15) - also fixes R5's phase-C read past ws.
// LDS 34816 B, 3 blocks/CU (register-capped, R4 lesson).
// Block mapping: proven decomposition (R1 lesson).
// -----------------------------------------------------------------------------
template<bool USE_HT>
__global__ __launch_bounds__(256, 3) void attn_kernel(const u16* __restrict__ h_p,
                                                      const u16* __restrict__ Mt_p,
                                                      const u16* __restrict__ WVt,
                                                      const u16* __restrict__ hT,
                                                      float* __restrict__ out) {
    constexpr int SMSZ = USE_HT ? 34816 : 53504;
    __shared__ __align__(16) char SM[SMSZ];
    u16*   Th  = (u16*)SM;                    // [32][260]
    u16*   Tl  = (u16*)(SM + 16640);          // [32][260]
    float* S   = (float*)SM;                  // [256][33]
    float* red = (float*)(SM + 33792);        // [256]
    u16*   HbT = (u16*)SM;                    // [512][36] (fallback only)
    u16*   U   = (u16*)SM;                    // [32][520]
    u16*   Pt  = (u16*)(SM + (USE_HT ? 0 : 36864)); // [32][260]

    const int bid = blockIdx.x;
    const int x7 = bid & 7;
    const int s  = bid >> 3;
    const int at = s & 1;
    const int n  = (x7 >> 1) | (((s >> 1) & 1) << 2);
    const int b  = ((s >> 2) << 1) | (x7 & 1);

    const int tid  = threadIdx.x;
    const int wid  = tid >> 6;
    const int lane = tid & 63;
    const int l15  = lane & 15;
    const int quad = lane >> 4;

    const u16* Mtp = Mt_p + (size_t)n * 524288;
    const u16* Wv  = WVt  + (size_t)n * 262144;
    const u16* hTb = hT + (size_t)b * 131072;
    const size_t hb_base = (size_t)b * 262144;            // packed rows of 1024
    const size_t ha_row0 = hb_base + (size_t)(at * 32) * 1024;

    const floatx4 z4 = {0.f, 0.f, 0.f, 0.f};
    floatx4 Sacc[8];
    #pragma unroll
    for (int i = 0; i < 8; ++i) Sacc[i] = z4;

    // per-lane base pointers (k-offset folded: +ks*64 u16 per packed k-block)
    const u16* hA  = h_p + ha_row0 + (size_t)l15 * 1024 + quad * 8;
    const u16* hB  = h_p + hb_base + (size_t)(wid * 64 + l15) * 1024 + quad * 8;

#define LDA4(SET, KS) do { const u16* _p = hA + (size_t)(KS) * 64;                     \
        SET##h0.s = *(const u32x4*)(_p);         SET##l0.s = *(const u32x4*)(_p + 32);   \
        SET##h1.s = *(const u32x4*)(_p + 16384); SET##l1.s = *(const u32x4*)(_p + 16416);} while (0)
#define LDB2(SET, KS, NT) do { const u16* _p = MtB + (NT) * 16384 + (size_t)(KS) * 64;  \
        SET##h.s = *(const u32x4*)(_p);          SET##l.s = *(const u32x4*)(_p + 32); } while (0)
#define MFA(AS, BS, NT) do {                                                            \
        floatx4 c0 = Tacc[NT], c1 = Tacc[4 + (NT)];                                     \
        c0 = mm(AS##h0, BS##h, c0); c0 = mm(AS##h0, BS##l, c0); c0 = mm(AS##l0, BS##h, c0); \
        c1 = mm(AS##h1, BS##h, c1); c1 = mm(AS##h1, BS##l, c1); c1 = mm(AS##l1, BS##h, c1); \
        Tacc[NT] = c0; Tacc[4 + (NT)] = c1; } while (0)
#define LDP8(SET, KO) do { const u16* _p = hB + (size_t)(KO) * 64;                      \
        SET##h0.s = *(const u32x4*)(_p);         SET##l0.s = *(const u32x4*)(_p + 32);   \
        SET##h1.s = *(const u32x4*)(_p + 16384); SET##l1.s = *(const u32x4*)(_p + 16416);\
        SET##h2.s = *(const u32x4*)(_p + 32768); SET##l2.s = *(const u32x4*)(_p + 32800);\
        SET##h3.s = *(const u32x4*)(_p + 49152); SET##l3.s = *(const u32x4*)(_p + 49184);} while (0)
#define MFMB(AS, KS) do {                                                               \
        const int _kl = (KS) * 32 + quad * 8;                                           \
        Frag _h0, _l0, _h1, _l1;                                                        \
        _h0.p.lo = *(const u32x2*)(Th + l15 * 260 + _kl);                               \
        _h0.p.hi = *(const u32x2*)(Th + l15 * 260 + _kl + 4);                           \
        _l0.p.lo = *(const u32x2*)(Tl + l15 * 260 + _kl);                               \
        _l0.p.hi = *(const u32x2*)(Tl + l15 * 260 + _kl + 4);                           \
        _h1.p.lo = *(const u32x2*)(Th + (16 + l15) * 260 + _kl);                        \
        _h1.p.hi = *(const u32x2*)(Th + (16 + l15) * 260 + _kl + 4);                    \
        _l1.p.lo = *(const u32x2*)(Tl + (16 + l15) * 260 + _kl);                        \
        _l1.p.hi = *(const u32x2*)(Tl + (16 + l15) * 260 + _kl + 4);                    \
        Sacc[0] = mm(AS##h0, _h0, Sacc[0]); Sacc[0] = mm(AS##h0, _l0, Sacc[0]); Sacc[0] = mm(AS##l0, _h0, Sacc[0]); \
        Sacc[2] = mm(AS##h1, _h0, Sacc[2]); Sacc[2] = mm(AS##h1, _l0, Sacc[2]); Sacc[2] = mm(AS##l1, _h0, Sacc[2]); \
        Sacc[4] = mm(AS##h2, _h0, Sacc[4]); Sacc[4] = mm(AS##h2, _l0, Sacc[4]); Sacc[4] = mm(AS##l2, _h0, Sacc[4]); \
        Sacc[6] = mm(AS##h3, _h0, Sacc[6]); Sacc[6] = mm(AS##h3, _l0, Sacc[6]); Sacc[6] = mm(AS##l3, _h0, Sacc[6]); \
        Sacc[1] = mm(AS##h0, _h1, Sacc[1]); Sacc[1] = mm(AS##h0, _l1, Sacc[1]); Sacc[1] = mm(AS##l0, _h1, Sacc[1]); \
        Sacc[3] = mm(AS##h1, _h1, Sacc[3]); Sacc[3] = mm(AS##h1, _l1, Sacc[3]); Sacc[3] = mm(AS##l1, _h1, Sacc[3]); \
        Sacc[5] = mm(AS##h2, _h1, Sacc[5]); Sacc[5] = mm(AS##h2, _l1, Sacc[5]); Sacc[5] = mm(AS##l2, _h1, Sacc[5]); \
        Sacc[7] = mm(AS##h3, _h1, Sacc[7]); Sacc[7] = mm(AS##h3, _l1, Sacc[7]); Sacc[7] = mm(AS##l3, _h1, Sacc[7]); } while (0)

    for (int H = 0; H < 2; ++H) {
        // ---------- Phase A (SB-pipelined): T = ha @ Mt ----------
        floatx4 Tacc[8];
        #pragma unroll
        for (int i = 0; i < 8; ++i) Tacc[i] = z4;
        const u16* MtB = Mtp + (size_t)(H * 256 + wid * 64 + l15) * 1024 + quad * 8;
        Frag A0h0, A0l0, A0h1, A0l1, A1h0, A1l0, A1h1, A1l1;
        Frag B0h, B0l, B1h, B1l, B2h, B2l, B3h, B3l;
        LDA4(A0, 0);
        LDB2(B0, 0, 0); LDB2(B1, 0, 1);
        for (int ks = 0; ks < 16; ks += 2) {
            LDA4(A1, ks + 1);
            LDB2(B2, ks, 2);             SB(); MFA(A0, B0, 0);
            LDB2(B3, ks, 3);             SB(); MFA(A0, B1, 1);
            LDB2(B0, ks + 1, 0);         SB(); MFA(A0, B2, 2);
            LDB2(B1, ks + 1, 1);         SB(); MFA(A0, B3, 3);
            LDA4(A0, (ks + 2) & 15);
            LDB2(B2, ks + 1, 2);         SB(); MFA(A1, B0, 0);
            LDB2(B3, ks + 1, 3);         SB(); MFA(A1, B1, 1);
            LDB2(B0, (ks + 2) & 15, 0);  SB(); MFA(A1, B2, 2);
            LDB2(B1, (ks + 2) & 15, 1);  SB(); MFA(A1, B3, 3);
        }
        // phase-B prologue prefetch: issued before the Tacc->LDS writes, its
        // latency overlaps them (the barrier's vmcnt(0) waits on completion).
        Frag P0h0, P0l0, P0h1, P0l1, P0h2, P0l2, P0h3, P0l3;
        Frag P1h0, P1l0, P1h1, P1l1, P1h2, P1l2, P1h3, P1l3;
        LDP8(P0, H * 8);
        __syncthreads();
        #pragma unroll
        for (int mt = 0; mt < 2; ++mt)
            #pragma unroll
            for (int nt = 0; nt < 4; ++nt)
                #pragma unroll
                for (int r = 0; r < 4; ++r) {
                    const float v = Tacc[mt * 4 + nt][r];
                    const int a  = mt * 16 + quad * 4 + r;
                    const int dl = (wid * 4 + nt) * 16 + l15;
                    const u16 hi = f2bf(v);
                    Th[a * 260 + dl] = hi;
                    Tl[a * 260 + dl] = f2bf(v - bf2f(hi));
                }
        __syncthreads();
        // ---------- Phase B (SB-pipelined): S^T += hb[:, H-half] @ T^T ------
        for (int ks = 0; ks < 8; ks += 2) {
            LDP8(P1, H * 8 + ks + 1);            SB(); MFMB(P0, ks);
            LDP8(P0, (H * 8 + ks + 2) & 15);     SB(); MFMB(P1, ks + 1);
        }
    }
    __syncthreads();
    #pragma unroll
    for (int mt = 0; mt < 4; ++mt)
        #pragma unroll
        for (int nt = 0; nt < 2; ++nt)
            #pragma unroll
            for (int r = 0; r < 4; ++r) {
                const int e = (wid * 4 + mt) * 16 + quad * 4 + r;
                const int a = nt * 16 + l15;
                S[e * 33 + a] = Sacc[mt * 2 + nt][r];
            }
    __syncthreads();
    // ---------- Softmax over e per agent ----------
    {
        const int a   = tid & 31;
        const int seg = tid >> 5;
        float v[32];
        #pragma unroll
        for (int i = 0; i < 32; ++i) v[i] = S[(seg * 32 + i) * 33 + a];
        float mx = v[0];
        #pragma unroll
        for (int i = 1; i < 32; ++i) mx = fmaxf(mx, v[i]);
        red[a * 8 + seg] = mx;
        __syncthreads();
        float gmx = red[a * 8 + 0];
        #pragma unroll
        for (int i = 1; i < 8; ++i) gmx = fmaxf(gmx, red[a * 8 + i]);
        __syncthreads();
        float sum = 0.f;
        #pragma unroll
        for (int i = 0; i < 32; ++i) { v[i] = expf(v[i] - gmx); sum += v[i]; }
        red[a * 8 + seg] = sum;
        __syncthreads();
        float tot = 0.f;
        #pragma unroll
        for (int i = 0; i < 8; ++i) tot += red[a * 8 + i];
        const float inv = 1.0f / tot;
        #pragma unroll
        for (int i = 0; i < 32; ++i)
            Pt[a * 260 + seg * 32 + i] = f2bf(v[i] * inv);
    }
    // ---------- Phase C: U = P @ hb ----------
    floatx4 Uacc[16];
    #pragma unroll
    for (int i = 0; i < 16; ++i) Uacc[i] = z4;
    const int d0w = wid * 128;
    if (USE_HT) {
        const u16* hTB = hTb + (size_t)(d0w + l15) * 256 + quad * 8;
#define LDC8(SET, ET) do { const u16* _p = hTB + (size_t)(ET) * 32;                     \
        SET##b0.s = *(const u32x4*)(_p);         SET##b1.s = *(const u32x4*)(_p + 4096); \
        SET##b2.s = *(const u32x4*)(_p + 8192);  SET##b3.s = *(const u32x4*)(_p + 12288);\
        SET##b4.s = *(const u32x4*)(_p + 16384); SET##b5.s = *(const u32x4*)(_p + 20480);\
        SET##b6.s = *(const u32x4*)(_p + 24576); SET##b7.s = *(const u32x4*)(_p + 28672);} while (0)
#define MFMC(SET, ET) do {                                                              \
        Frag _a0, _a1;                                                                  \
        _a0.p.lo = *(const u32x2*)(Pt + l15 * 260 + (ET) * 32 + quad * 8);              \
        _a0.p.hi = *(const u32x2*)(Pt + l15 * 260 + (ET) * 32 + quad * 8 + 4);          \
        _a1.p.lo = *(const u32x2*)(Pt + (16 + l15) * 260 + (ET) * 32 + quad * 8);       \
        _a1.p.hi = *(const u32x2*)(Pt + (16 + l15) * 260 + (ET) * 32 + quad * 8 + 4);   \
        Uacc[0] = mm(_a0, SET##b0, Uacc[0]);  Uacc[8]  = mm(_a1, SET##b0, Uacc[8]);     \
        Uacc[1] = mm(_a0, SET##b1, Uacc[1]);  Uacc[9]  = mm(_a1, SET##b1, Uacc[9]);     \
        Uacc[2] = mm(_a0, SET##b2, Uacc[2]);  Uacc[10] = mm(_a1, SET##b2, Uacc[10]);    \
        Uacc[3] = mm(_a0, SET##b3, Uacc[3]);  Uacc[11] = mm(_a1, SET##b3, Uacc[11]);    \
        Uacc[4] = mm(_a0, SET##b4, Uacc[4]);  Uacc[12] = mm(_a1, SET##b4, Uacc[12]);    \
        Uacc[5] = mm(_a0, SET##b5, Uacc[5]);  Uacc[13] = mm(_a1, SET##b5, Uacc[13]);    \
        Uacc[6] = mm(_a0, SET##b6, Uacc[6]);  Uacc[14] = mm(_a1, SET##b6, Uacc[14]);    \
        Uacc[7] = mm(_a0, SET##b7, Uacc[7]);  Uacc[15] = mm(_a1, SET##b7, Uacc[15]); } while (0)
        Frag C0b0, C0b1, C0b2, C0b3, C0b4, C0b5, C0b6, C0b7;
        Frag C1b0, C1b1, C1b2, C1b3, C1b4, C1b5, C1b6, C1b7;
        LDC8(C0, 0);               // prologue issued before the barrier
        __syncthreads();
        for (int et = 0; et < 8; et += 2) {
            LDC8(C1, et + 1);            SB(); MFMC(C0, et);
            LDC8(C0, (et + 2) & 7);      SB(); MFMC(C1, et + 1);
        }
#undef LDC8
#undef MFMC
    } else {
        __syncthreads();
        // fallback: pair-packed in-LDS transpose from packed h (hi halves)
        u32* Hb32 = (u32*)HbT;
        for (int et = 0; et < 8; ++et) {
            {
                const int epi = lane & 15;
                const int q   = lane >> 4;
                const size_t r0p = hb_base + (size_t)(et * 32 + 2 * epi) * 1024;
                #pragma unroll
                for (int c = 0; c < 4; ++c) {
                    const int d0 = d0w + c * 32 + q * 8;
                    const size_t po = (size_t)(d0 >> 5) * 64 + (d0 & 31);
                    u32x4 u0 = *(const u32x4*)(h_p + r0p + po);
                    u32x4 u1 = *(const u32x4*)(h_p + r0p + 1024 + po);
                    #pragma unroll
                    for (int p = 0; p < 4; ++p) {
                        const u32 w0 = (u0[p] & 0xFFFFu) | (u1[p] << 16);
                        const u32 w1 = (u0[p] >> 16) | (u1[p] & 0xFFFF0000u);
                        Hb32[(d0 + 2 * p) * 18 + epi]     = w0;
                        Hb32[(d0 + 2 * p + 1) * 18 + epi] = w1;
                    }
                }
            }
            Frag Ap[2];
            #pragma unroll
            for (int mt = 0; mt < 2; ++mt) {
                const int ar = mt * 16 + l15;
                Ap[mt].p.lo = *(const u32x2*)(Pt + ar * 260 + et * 32 + quad * 8);
                Ap[mt].p.hi = *(const u32x2*)(Pt + ar * 260 + et * 32 + quad * 8 + 4);
            }
            #pragma unroll
            for (int dt = 0; dt < 8; ++dt) {
                const int d = d0w + dt * 16 + l15;
                Frag Bf;
                Bf.p.lo = *(const u32x2*)(HbT + d * 36 + quad * 8);
                Bf.p.hi = *(const u32x2*)(HbT + d * 36 + quad * 8 + 4);
                #pragma unroll
                for (int mt = 0; mt < 2; ++mt)
                    Uacc[mt * 8 + dt] = __builtin_amdgcn_mfma_f32_16x16x32_bf16(
                        Ap[mt].v, Bf.v, Uacc[mt * 8 + dt], 0, 0, 0);
            }
        }
    }
    __syncthreads();
    #pragma unroll
    for (int mt = 0; mt < 2; ++mt)
        #pragma unroll
        for (int dt = 0; dt < 8; ++dt)
            #pragma unroll
            for (int r = 0; r < 4; ++r) {
                const int a = mt * 16 + quad * 4 + r;
                const int d = d0w + dt * 16 + l15;
                U[a * 520 + d] = f2bf(Uacc[mt * 8 + dt][r]);
            }
    // ---------- Phase D (SB-pipelined): z = U @ WVt ----------
    floatx4 Zacc[16];
    #pragma unroll
    for (int i = 0; i < 16; ++i) Zacc[i] = z4;
    const u16* WvB = Wv + (size_t)(wid * 128 + l15) * 512 + quad * 8;
#define LDD8(SET, KS) do { const u16* _p = WvB + (size_t)(KS) * 32;                     \
        SET##b0.s = *(const u32x4*)(_p);         SET##b1.s = *(const u32x4*)(_p + 8192); \
        SET##b2.s = *(const u32x4*)(_p + 16384); SET##b3.s = *(const u32x4*)(_p + 24576);\
        SET##b4.s = *(const u32x4*)(_p + 32768); SET##b5.s = *(const u32x4*)(_p + 40960);\
        SET##b6.s = *(const u32x4*)(_p + 49152); SET##b7.s = *(const u32x4*)(_p + 57344);} while (0)
#define MFMD(SET, KS) do {                                                              \
        Frag _a0, _a1;                                                                  \
        _a0.p.lo = *(const u32x2*)(U + l15 * 520 + (KS) * 32 + quad * 8);               \
        _a0.p.hi = *(const u32x2*)(U + l15 * 520 + (KS) * 32 + quad * 8 + 4);           \
        _a1.p.lo = *(const u32x2*)(U + (16 + l15) * 520 + (KS) * 32 + quad * 8);        \
        _a1.p.hi = *(const u32x2*)(U + (16 + l15) * 520 + (KS) * 32 + quad * 8 + 4);    \
        Zacc[0] = mm(_a0, SET##b0, Zacc[0]);  Zacc[8]  = mm(_a1, SET##b0, Zacc[8]);     \
        Zacc[1] = mm(_a0, SET##b1, Zacc[1]);  Zacc[9]  = mm(_a1, SET##b1, Zacc[9]);     \
        Zacc[2] = mm(_a0, SET##b2, Zacc[2]);  Zacc[10] = mm(_a1, SET##b2, Zacc[10]);    \
        Zacc[3] = mm(_a0, SET##b3, Zacc[3]);  Zacc[11] = mm(_a1, SET##b3, Zacc[11]);    \
        Zacc[4] = mm(_a0, SET##b4, Zacc[4]);  Zacc[12] = mm(_a1, SET##b4, Zacc[12]);    \
        Zacc[5] = mm(_a0, SET##b5, Zacc[5]);  Zacc[13] = mm(_a1, SET##b5, Zacc[13]);    \
        Zacc[6] = mm(_a0, SET##b6, Zacc[6]);  Zacc[14] = mm(_a1, SET##b6, Zacc[14]);    \
        Zacc[7] = mm(_a0, SET##b7, Zacc[7]);  Zacc[15] = mm(_a1, SET##b7, Zacc[15]); } while (0)
    Frag D0b0, D0b1, D0b2, D0b3, D0b4, D0b5, D0b6, D0b7;
    Frag D1b0, D1b1, D1b2, D1b3, D1b4, D1b5, D1b6, D1b7;
    LDD8(D0, 0);                   // prologue issued before the barrier
    __syncthreads();
    for (int ks = 0; ks < 16; ks += 2) {
        LDD8(D1, ks + 1);            SB(); MFMD(D0, ks);
        LDD8(D0, (ks + 2) & 15);     SB(); MFMD(D1, ks + 1);
    }
#undef LDD8
#undef MFMD
#undef LDA4
#undef LDB2
#undef MFA
#undef LDP8
#undef MFMB
    float* ob = out + ((size_t)b * NAGENT + at * 32) * HID;
    #pragma unroll
    for (int mt = 0; mt < 2; ++mt)
        #pragma unroll
        for (int dt = 0; dt < 8; ++dt)
            #pragma unroll
            for (int r = 0; r < 4; ++r) {
                const int a  = mt * 16 + quad * 4 + r;
                const int dn = (wid * 8 + dt) * 16 + l15;
                atomicAdd(ob + (size_t)a * HID + dn, Zacc[mt * 8 + dt][r] * 0.125f);
            }
}

// -----------------------------------------------------------------------------
// ws layout: h_p 64M [0,64M) | Mt_p 8M [64M,72M) | WVt 4M [72M,76M)
//            | hT 32M [76M,108M) (useHT iff ws >= 108 MB)
// Wt_p (512 KB) transiently lives at WVt start: wenc_t -> enc -> wvt overwrites.
// -----------------------------------------------------------------------------
extern "C" void kernel_launch(void* const* d_in, const int* in_sizes, int n_in,
                              void* d_out, int out_size, void* d_ws, size_t ws_size,
                              hipStream_t stream) {
    const float* x     = (const float*)d_in[0];
    const float* W_enc = (const float*)d_in[1];
    const float* b_enc = (const float*)d_in[2];
    const float* WQ    = (const float*)d_in[3];
    const float* WK    = (const float*)d_in[4];
    const float* WV    = (const float*)d_in[5];
    float* out = (float*)d_out;

    char* ws = (char*)d_ws;
    u16* h_p  = (u16*)ws;
    u16* Mt_p = (u16*)(ws + 67108864);
    u16* WVt  = (u16*)(ws + 75497472);
    u16* hT   = (u16*)(ws + 79691776);
    u16* Wt_p = WVt;                       // transient, 512 KB

    const bool useHT = ws_size >= (size_t)113246208;  // 108 MB

    hipMemsetAsync(d_out, 0, (size_t)out_size * sizeof(float), stream);
    wenc_t_kernel<<<32, 256, 0, stream>>>(W_enc, Wt_p);
    enc_kernel<<<1024, 256, 0, stream>>>(x, Wt_p, b_enc, h_p);
    if (useHT) ht_kernel<<<4096, 256, 0, stream>>>(h_p, hT);
    wvt_kernel<<<512, 256, 0, stream>>>(WV, WVt);
    wqk_kernel<<<512, 256, 0, stream>>>(WQ, WK, Mt_p);
    if (useHT)
        attn_kernel<true><<<2048, 256, 0, stream>>>(h_p, Mt_p, WVt, hT, out);
    else
        attn_kernel<false><<<2048, 256, 0, stream>>>(h_p, Mt_p, WVt, hT, out);
}

// Round 7
// 894.511 us; speedup vs baseline: 1.1158x; 1.1158x over previous
//
#include <hip/hip_runtime.h>
#include <math.h>

#define BATCH  128
#define NENT   256
#define INDIM  256
#define HID    512
#define NHEAD  8
#define NAGENT 64
#define SCALE  0.04419417382415922f   // 1/sqrt(512)

// Packed split-bf16 layout: row-major rows of k-blocks; each 32-k block is
// 128 B = [32 x u16 hi | 32 x u16 lo] -> one full cache line per frag pair.
// h_p:  [32768][16 blk][64]  (64 MB)   Mt_p: [8][512][16 blk][64] (8 MB)
// Wt_p: [512][8 blk][64] (512 KB, transient)

typedef unsigned short u16;
typedef unsigned int   u32;

typedef __bf16 bf16x8  __attribute__((ext_vector_type(8)));
typedef float  floatx4 __attribute__((ext_vector_type(4)));
typedef u32    u32x4   __attribute__((ext_vector_type(4)));
typedef u32    u32x2   __attribute__((ext_vector_type(2)));

union Frag {
    u32x4 s;
    struct { u32x2 lo, hi; } p;
    bf16x8 v;
};

__device__ __forceinline__ u16 f2bf(float x) {
    u32 u = __float_as_uint(x);
    return (u16)((u + 0x7FFFu + ((u >> 16) & 1u)) >> 16);
}
__device__ __forceinline__ float bf2f(u16 b) {
    return __uint_as_float(((u32)b) << 16);
}
__device__ __forceinline__ void split4(const float4& r, ushort4& hh, ushort4& hl) {
    hh.x = f2bf(r.x); hl.x = f2bf(r.x - bf2f(hh.x));
    hh.y = f2bf(r.y); hl.y = f2bf(r.y - bf2f(hh.y));
    hh.z = f2bf(r.z); hl.z = f2bf(r.z - bf2f(hh.z));
    hh.w = f2bf(r.w); hl.w = f2bf(r.w - bf2f(hh.w));
}
__device__ __forceinline__ floatx4 mm(const Frag& a, const Frag& b, floatx4 c) {
    return __builtin_amdgcn_mfma_f32_16x16x32_bf16(a.v, b.v, c, 0, 0, 0);
}
// Async global->LDS, 16B per lane, no VGPR destination (vmcnt-tracked).
// LDS dest must be wave-uniform base (+ lane*16 implicit); global src per-lane.
__device__ __forceinline__ void gl16(const u16* g, char* l) {
    __builtin_amdgcn_global_load_lds(
        (const __attribute__((address_space(1))) u32*)g,
        (__attribute__((address_space(3))) u32*)l, 16, 0, 0);
}

// -----------------------------------------------------------------------------
// K0: Wt_p[d][k] = packed split(W_enc[k][d])  (transpose), 512 x 256
// -----------------------------------------------------------------------------
__global__ __launch_bounds__(256) void wenc_t_kernel(const float* __restrict__ W,
                                                     u16* __restrict__ Wt_p) {
    __shared__ float tile[64][68];
    const int bid = blockIdx.x;          // 4 k-tiles x 8 d-tiles
    const int k0 = (bid & 3) * 64;
    const int d0 = (bid >> 2) * 64;
    const int t = threadIdx.x;
    const int ki = t >> 2, dc = (t & 3) * 16;
    #pragma unroll
    for (int c = 0; c < 4; ++c)
        *(float4*)&tile[ki][dc + c * 4] =
            *(const float4*)(W + (size_t)(k0 + ki) * HID + d0 + dc + c * 4);
    __syncthreads();
    const int dr = t >> 2, kc = (t & 3) * 16;
    #pragma unroll
    for (int c = 0; c < 4; ++c) {
        float4 v = make_float4(tile[kc + c * 4 + 0][dr], tile[kc + c * 4 + 1][dr],
                               tile[kc + c * 4 + 2][dr], tile[kc + c * 4 + 3][dr]);
        ushort4 hh, hl; split4(v, hh, hl);
        const int kk = k0 + kc + c * 4;
        size_t o = (size_t)(d0 + dr) * 512 + (size_t)(kk >> 5) * 64 + (kk & 31);
        *(ushort4*)(Wt_p + o) = hh;
        *(ushort4*)(Wt_p + o + 32) = hl;
    }
}

// -----------------------------------------------------------------------------
// K1: h = leaky_relu(x) @ W_enc + b_enc via split-bf16 3-pass MFMA -> h_p packed
// -----------------------------------------------------------------------------
__global__ __launch_bounds__(256) void enc_kernel(const float* __restrict__ x,
                                                  const u16* __restrict__ Wt_p,
                                                  const float* __restrict__ bias,
                                                  u16* __restrict__ h_p) {
    __shared__ u16 Ah[32][264];
    __shared__ u16 Al[32][264];
    const int r0 = blockIdx.x * 32;
    const int t  = threadIdx.x;
    {
        const int row = t >> 3;
        const float* xr = x + (size_t)(r0 + row) * INDIM;
        #pragma unroll
        for (int j = 0; j < 8; ++j) {
            const int k0 = ((t & 7) + j * 8) * 4;
            float4 v = *(const float4*)(xr + k0);
            v.x = v.x > 0.f ? v.x : 0.01f * v.x;
            v.y = v.y > 0.f ? v.y : 0.01f * v.y;
            v.z = v.z > 0.f ? v.z : 0.01f * v.z;
            v.w = v.w > 0.f ? v.w : 0.01f * v.w;
            ushort4 hh, hl; split4(v, hh, hl);
            *(ushort4*)&Ah[row][k0] = hh;
            *(ushort4*)&Al[row][k0] = hl;
        }
    }
    __syncthreads();

    const int wid = t >> 6, lane = t & 63, l15 = lane & 15, quad = lane >> 4;
    const int mbase = (wid & 1) * 16;
    const int nbase = (wid >> 1) * 256;
    const floatx4 z4 = {0.f, 0.f, 0.f, 0.f};
    floatx4 acc[16];
    #pragma unroll
    for (int i = 0; i < 16; ++i) acc[i] = z4;

    for (int ks = 0; ks < 8; ++ks) {
        const int k = ks * 32 + quad * 8;
        Frag Afh, Afl;
        Afh.s = *(const u32x4*)&Ah[mbase + l15][k];
        Afl.s = *(const u32x4*)&Al[mbase + l15][k];
        #pragma unroll
        for (int nt = 0; nt < 16; ++nt) {
            const int d = nbase + nt * 16 + l15;
            const size_t wo = (size_t)d * 512 + (size_t)ks * 64 + quad * 8;
            Frag Bh, Bl;
            Bh.s = *(const u32x4*)(Wt_p + wo);
            Bl.s = *(const u32x4*)(Wt_p + wo + 32);
            floatx4 c = acc[nt];
            c = __builtin_amdgcn_mfma_f32_16x16x32_bf16(Afh.v, Bh.v, c, 0, 0, 0);
            c = __builtin_amdgcn_mfma_f32_16x16x32_bf16(Afh.v, Bl.v, c, 0, 0, 0);
            c = __builtin_amdgcn_mfma_f32_16x16x32_bf16(Afl.v, Bh.v, c, 0, 0, 0);
            acc[nt] = c;
        }
    }
    #pragma unroll
    for (int nt = 0; nt < 16; ++nt) {
        const int d = nbase + nt * 16 + l15;
        const float bv = bias[d];
        #pragma unroll
        for (int r = 0; r < 4; ++r) {
            const float v = acc[nt][r] + bv;
            const u16 hi = f2bf(v);
            const u16 lo = f2bf(v - bf2f(hi));
            const size_t o = (size_t)(r0 + mbase + quad * 4 + r) * 1024
                           + (size_t)(d >> 5) * 64 + (d & 31);
            h_p[o]      = hi;
            h_p[o + 32] = lo;
        }
    }
}

// -----------------------------------------------------------------------------
// K1b: hT[b][d][e] = hi(h[b*256+e][d])  (64x64 u16 tile transpose, from packed)
// -----------------------------------------------------------------------------
__global__ __launch_bounds__(256) void ht_kernel(const u16* __restrict__ h_p,
                                                 u16* __restrict__ hT) {
    __shared__ u16 tile[64][72];
    const int bid = blockIdx.x;               // 8 dt x 4 et x 128 b
    const int dt = bid & 7;
    const int et = (bid >> 3) & 3;
    const int b  = bid >> 5;
    const int t  = threadIdx.x;
    const int r  = t >> 2, cs = (t & 3) * 16;
    const int dg = dt * 64 + cs;
    const u16* src = h_p + (size_t)(b * 256 + et * 64 + r) * 1024
                   + (size_t)(dg >> 5) * 64 + (dg & 31);
    *(ushort4*)&tile[r][cs + 0]  = *(const ushort4*)(src + 0);
    *(ushort4*)&tile[r][cs + 4]  = *(const ushort4*)(src + 4);
    *(ushort4*)&tile[r][cs + 8]  = *(const ushort4*)(src + 8);
    *(ushort4*)&tile[r][cs + 12] = *(const ushort4*)(src + 12);
    __syncthreads();
    const int d = t >> 2, es = (t & 3) * 16;
    u16* dst = hT + (size_t)b * 131072 + (size_t)(dt * 64 + d) * 256 + et * 64 + es;
    #pragma unroll
    for (int c = 0; c < 4; ++c) {
        ushort4 v = make_ushort4(tile[es + c * 4 + 0][d], tile[es + c * 4 + 1][d],
                                 tile[es + c * 4 + 2][d], tile[es + c * 4 + 3][d]);
        *(ushort4*)(dst + c * 4) = v;
    }
}

// -----------------------------------------------------------------------------
// K2: Mt_p[n][j][i] = packed split(SCALE * dot(WQ[n][i,:], WK[n][j,:]))
// -----------------------------------------------------------------------------
__global__ __launch_bounds__(256) void wqk_kernel(const float* __restrict__ WQ,
                                                  const float* __restrict__ WK,
                                                  u16* __restrict__ Mt_p) {
    __shared__ u16 Ah[64][72], Al[64][72], Bh[64][72], Bl[64][72];
    const int bid = blockIdx.x;
    const int jt = (bid & 7) * 64;
    const int it = ((bid >> 3) & 7) * 64;
    const int n  = bid >> 6;
    const float* qp = WQ + (size_t)n * 262144;
    const float* kp = WK + (size_t)n * 262144;
    const int t = threadIdx.x;
    const int wid = t >> 6, lane = t & 63, l15 = lane & 15, quad = lane >> 4;
    const int srow = t >> 2, sc = (t & 3) * 16;

    const floatx4 z4 = {0.f, 0.f, 0.f, 0.f};
    floatx4 acc[4];
    #pragma unroll
    for (int i = 0; i < 4; ++i) acc[i] = z4;

    for (int kc = 0; kc < HID; kc += 64) {
        #pragma unroll
        for (int f = 0; f < 4; ++f) {
            float4 va = *(const float4*)(kp + (size_t)(jt + srow) * HID + kc + sc + f * 4);
            ushort4 hh, hl; split4(va, hh, hl);
            *(ushort4*)&Ah[srow][sc + f * 4] = hh;
            *(ushort4*)&Al[srow][sc + f * 4] = hl;
            float4 vb = *(const float4*)(qp + (size_t)(it + srow) * HID + kc + sc + f * 4);
            split4(vb, hh, hl);
            *(ushort4*)&Bh[srow][sc + f * 4] = hh;
            *(ushort4*)&Bl[srow][sc + f * 4] = hl;
        }
        __syncthreads();
        #pragma unroll
        for (int ks = 0; ks < 2; ++ks) {
            const int k = ks * 32 + quad * 8;
            Frag Afh, Afl;
            Afh.s = *(const u32x4*)&Ah[wid * 16 + l15][k];
            Afl.s = *(const u32x4*)&Al[wid * 16 + l15][k];
            #pragma unroll
            for (int nt = 0; nt < 4; ++nt) {
                Frag Bfh, Bfl;
                Bfh.s = *(const u32x4*)&Bh[nt * 16 + l15][k];
                Bfl.s = *(const u32x4*)&Bl[nt * 16 + l15][k];
                floatx4 c = acc[nt];
                c = __builtin_amdgcn_mfma_f32_16x16x32_bf16(Afh.v, Bfh.v, c, 0, 0, 0);
                c = __builtin_amdgcn_mfma_f32_16x16x32_bf16(Afh.v, Bfl.v, c, 0, 0, 0);
                c = __builtin_amdgcn_mfma_f32_16x16x32_bf16(Afl.v, Bfh.v, c, 0, 0, 0);
                acc[nt] = c;
            }
        }
        __syncthreads();
    }
    #pragma unroll
    for (int nt = 0; nt < 4; ++nt)
        #pragma unroll
        for (int r = 0; r < 4; ++r) {
            const float v = acc[nt][r] * SCALE;
            const u16 hi = f2bf(v);
            const u16 lo = f2bf(v - bf2f(hi));
            const int j = jt + wid * 16 + quad * 4 + r;
            const int i = it + nt * 16 + l15;
            const size_t o = (size_t)n * 524288 + (size_t)j * 1024
                           + (size_t)(i >> 5) * 64 + (i & 31);
            Mt_p[o]      = hi;
            Mt_p[o + 32] = lo;
        }
}

// -----------------------------------------------------------------------------
// K3: WVt[n][dout][din] = bf16(WV[n][din][dout])
// -----------------------------------------------------------------------------
__global__ __launch_bounds__(256) void wvt_kernel(const float* __restrict__ WV,
                                                  u16* __restrict__ WVt) {
    __shared__ float tile[64][68];
    const int bid = blockIdx.x;
    const int i0 = (bid & 7) * 64;
    const int o0 = ((bid >> 3) & 7) * 64;
    const int n  = bid >> 6;
    const float* src = WV + (size_t)n * 262144;
    const int t  = threadIdx.x;
    const int di = t >> 2;
    const int dc = (t & 3) * 16;
    #pragma unroll
    for (int c = 0; c < 4; ++c)
        *(float4*)&tile[di][dc + c * 4] =
            *(const float4*)(src + (size_t)(i0 + di) * HID + o0 + dc + c * 4);
    __syncthreads();
    const int dr = t >> 2;
    const int ic = (t & 3) * 16;
    size_t o = (size_t)n * 262144 + (size_t)(o0 + dr) * HID + i0 + ic;
    #pragma unroll
    for (int c = 0; c < 4; ++c) {
        ushort4 v = make_ushort4(f2bf(tile[ic + c * 4 + 0][dr]), f2bf(tile[ic + c * 4 + 1][dr]),
                                 f2bf(tile[ic + c * 4 + 2][dr]), f2bf(tile[ic + c * 4 + 3][dr]));
        *(ushort4*)(WVt + o + c * 4) = v;
    }
}

// -----------------------------------------------------------------------------
// K4: fused MFMA attention. Phase A now uses global_load_lds cooperative
// staging (R5/R6 lesson: hipcc will NOT hold batched global->VGPR loads in
// flight — it collapses the schedule (R5) or spills (R6). global_load_lds has
// NO VGPR destination, so 9 loads/thread sit in flight and drain with one
// vmcnt at the barrier — the m97-proven pattern).
// Per (H,ks): stage Mt slab [8 chunk][256 row][16B] (32KB) + ha slab
// [8][32][16B] (4KB); barrier; 24 MFMAs/wave from LDS; barrier. Chunked layout
// makes BOTH the linear wave-write and the ds_read_b128 frag reads
// conflict-free (16B row stride -> 2-way max, free per m136). No swizzle.
// Staging region [0,36864) time-multiplexes with Th/Tl -> S -> Pt -> U
// (barriers already guard each transition; top-of-H barrier added so async
// LDS writes can't land while prev phase B still reads Th/Tl).
// LDS total 37888 B -> 3 blocks/CU (register-capped anyway, R4 lesson).
// Phases B/C/D: R4-proven direct-load versions, untouched.
// Spill tripwire: WRITE_SIZE must stay exactly 131072 KB (R1-R3/R6 lesson).
// Block mapping: proven decomposition (R1 lesson).
// -----------------------------------------------------------------------------
template<bool USE_HT>
__global__ __launch_bounds__(256, 3) void attn_kernel(const u16* __restrict__ h_p,
                                                      const u16* __restrict__ Mt_p,
                                                      const u16* __restrict__ WVt,
                                                      const u16* __restrict__ hT,
                                                      float* __restrict__ out) {
    constexpr int SMSZ = USE_HT ? 37888 : 53504;
    __shared__ __align__(16) char SM[SMSZ];
    u16*   Th  = (u16*)SM;                    // [32][260]
    u16*   Tl  = (u16*)(SM + 16640);          // [32][260]
    float* S   = (float*)SM;                  // [256][33]
    float* red = (float*)(SM + (USE_HT ? 36864 : 33792)); // [256]
    u16*   HbT = (u16*)SM;                    // [512][36] (fallback only)
    u16*   U   = (u16*)SM;                    // [32][520]
    u16*   Pt  = (u16*)(SM + (USE_HT ? 0 : 36864)); // [32][260]

    const int bid = blockIdx.x;
    const int x7 = bid & 7;
    const int s  = bid >> 3;
    const int at = s & 1;
    const int n  = (x7 >> 1) | (((s >> 1) & 1) << 2);
    const int b  = ((s >> 2) << 1) | (x7 & 1);

    const int tid  = threadIdx.x;
    const int wid  = tid >> 6;
    const int lane = tid & 63;
    const int l15  = lane & 15;
    const int quad = lane >> 4;

    const u16* Mtp = Mt_p + (size_t)n * 524288;
    const u16* Wv  = WVt  + (size_t)n * 262144;
    const u16* hTb = hT + (size_t)b * 131072;
    const size_t hb_base = (size_t)b * 262144;            // packed rows of 1024
    const size_t ha_row0 = hb_base + (size_t)(at * 32) * 1024;

    const floatx4 z4 = {0.f, 0.f, 0.f, 0.f};
    floatx4 Sacc[8];
    #pragma unroll
    for (int i = 0; i < 8; ++i) Sacc[i] = z4;

    for (int H = 0; H < 2; ++H) {
        // ---------- Phase A (LDS-staged): T = ha @ Mt ----------
        __syncthreads();   // staging region free (prev Th/Tl fully consumed)
        floatx4 Tacc[8];
        #pragma unroll
        for (int i = 0; i < 8; ++i) Tacc[i] = z4;
        const int d0 = H * 256;
        const u16* mtS = (const u16*)SM;            // [8][256][16B] slab
        const u16* haS = (const u16*)(SM + 32768);  // [8][32][16B] slab
        for (int ks = 0; ks < 16; ++ks) {
            // Stage Mt slab: 32 wave-instructions (8/thread), 1 KB each.
            // i = wid*8+j: chunk = i>>2, rows (i&3)*64 + lane.
            #pragma unroll
            for (int j = 0; j < 8; ++j) {
                const int i = wid * 8 + j;
                const int chunk = i >> 2;
                const int row   = (i & 3) * 64 + lane;
                gl16(Mtp + (size_t)(d0 + row) * 1024 + ks * 64 + chunk * 8,
                     SM + i * 1024);
            }
            // Stage ha slab: 4 wave-instructions (1/thread).
            {
                const int chunk = wid * 2 + (lane >> 5);
                const int row   = lane & 31;
                gl16(h_p + ha_row0 + (size_t)row * 1024 + ks * 64 + chunk * 8,
                     SM + 32768 + wid * 1024);
            }
            __syncthreads();   // drains vmcnt(0): slab ready
            Frag Ah0, Al0, Ah1, Al1;
            Ah0.s = *(const u32x4*)(haS + ((quad)     * 32 + l15)      * 8);
            Al0.s = *(const u32x4*)(haS + ((4 + quad) * 32 + l15)      * 8);
            Ah1.s = *(const u32x4*)(haS + ((quad)     * 32 + 16 + l15) * 8);
            Al1.s = *(const u32x4*)(haS + ((4 + quad) * 32 + 16 + l15) * 8);
            #pragma unroll
            for (int nt = 0; nt < 4; ++nt) {
                const int row = (wid * 4 + nt) * 16 + l15;
                Frag Bh, Bl;
                Bh.s = *(const u32x4*)(mtS + ((quad)     * 256 + row) * 8);
                Bl.s = *(const u32x4*)(mtS + ((4 + quad) * 256 + row) * 8);
                floatx4 c0 = Tacc[nt], c1 = Tacc[4 + nt];
                c0 = mm(Ah0, Bh, c0); c0 = mm(Ah0, Bl, c0); c0 = mm(Al0, Bh, c0);
                c1 = mm(Ah1, Bh, c1); c1 = mm(Ah1, Bl, c1); c1 = mm(Al1, Bh, c1);
                Tacc[nt] = c0; Tacc[4 + nt] = c1;
            }
            __syncthreads();   // all waves done with slab before next overwrite
        }
        // staging region dead -> write Th/Tl into it
        #pragma unroll
        for (int mt = 0; mt < 2; ++mt)
            #pragma unroll
            for (int nt = 0; nt < 4; ++nt)
                #pragma unroll
                for (int r = 0; r < 4; ++r) {
                    const float v = Tacc[mt * 4 + nt][r];
                    const int a  = mt * 16 + quad * 4 + r;
                    const int dl = (wid * 4 + nt) * 16 + l15;
                    const u16 hi = f2bf(v);
                    Th[a * 260 + dl] = hi;
                    Tl[a * 260 + dl] = f2bf(v - bf2f(hi));
                }
        __syncthreads();
        // ---------- Phase B: S^T += hb[:, H-half] @ T^T ----------
        for (int ks = 0; ks < 8; ++ks) {
            const int kl = ks * 32 + quad * 8;            // local (LDS) k
            const int ko = (H * 8 + ks) * 64 + quad * 8;  // packed global k
            Frag Ahf[4], Alf[4];
            #pragma unroll
            for (int mt = 0; mt < 4; ++mt) {
                const size_t ro = hb_base + (size_t)((wid * 4 + mt) * 16 + l15) * 1024 + ko;
                Ahf[mt].s = *(const u32x4*)(h_p + ro);
                Alf[mt].s = *(const u32x4*)(h_p + ro + 32);
            }
            #pragma unroll
            for (int nt = 0; nt < 2; ++nt) {
                const int ac = nt * 16 + l15;
                Frag Bfh, Bfl;
                Bfh.p.lo = *(const u32x2*)(Th + ac * 260 + kl);
                Bfh.p.hi = *(const u32x2*)(Th + ac * 260 + kl + 4);
                Bfl.p.lo = *(const u32x2*)(Tl + ac * 260 + kl);
                Bfl.p.hi = *(const u32x2*)(Tl + ac * 260 + kl + 4);
                #pragma unroll
                for (int mt = 0; mt < 4; ++mt) {
                    floatx4 c = Sacc[mt * 2 + nt];
                    c = __builtin_amdgcn_mfma_f32_16x16x32_bf16(Ahf[mt].v, Bfh.v, c, 0, 0, 0);
                    c = __builtin_amdgcn_mfma_f32_16x16x32_bf16(Ahf[mt].v, Bfl.v, c, 0, 0, 0);
                    c = __builtin_amdgcn_mfma_f32_16x16x32_bf16(Alf[mt].v, Bfh.v, c, 0, 0, 0);
                    Sacc[mt * 2 + nt] = c;
                }
            }
        }
    }
    __syncthreads();
    #pragma unroll
    for (int mt = 0; mt < 4; ++mt)
        #pragma unroll
        for (int nt = 0; nt < 2; ++nt)
            #pragma unroll
            for (int r = 0; r < 4; ++r) {
                const int e = (wid * 4 + mt) * 16 + quad * 4 + r;
                const int a = nt * 16 + l15;
                S[e * 33 + a] = Sacc[mt * 2 + nt][r];
            }
    __syncthreads();
    // ---------- Softmax over e per agent ----------
    {
        const int a   = tid & 31;
        const int seg = tid >> 5;
        float v[32];
        #pragma unroll
        for (int i = 0; i < 32; ++i) v[i] = S[(seg * 32 + i) * 33 + a];
        float mx = v[0];
        #pragma unroll
        for (int i = 1; i < 32; ++i) mx = fmaxf(mx, v[i]);
        red[a * 8 + seg] = mx;
        __syncthreads();
        float gmx = red[a * 8 + 0];
        #pragma unroll
        for (int i = 1; i < 8; ++i) gmx = fmaxf(gmx, red[a * 8 + i]);
        __syncthreads();
        float sum = 0.f;
        #pragma unroll
        for (int i = 0; i < 32; ++i) { v[i] = expf(v[i] - gmx); sum += v[i]; }
        red[a * 8 + seg] = sum;
        __syncthreads();
        float tot = 0.f;
        #pragma unroll
        for (int i = 0; i < 8; ++i) tot += red[a * 8 + i];
        const float inv = 1.0f / tot;
        #pragma unroll
        for (int i = 0; i < 32; ++i)
            Pt[a * 260 + seg * 32 + i] = f2bf(v[i] * inv);
    }
    __syncthreads();
    // ---------- Phase C: U = P @ hb ----------
    floatx4 Uacc[16];
    #pragma unroll
    for (int i = 0; i < 16; ++i) Uacc[i] = z4;
    const int d0w = wid * 128;
    if (USE_HT) {
        // et-paired: both 64B halves of each hT line consumed together
        for (int ep = 0; ep < 4; ++ep) {
            Frag Bc[2][8];
            #pragma unroll
            for (int sb = 0; sb < 2; ++sb)
                #pragma unroll
                for (int dt = 0; dt < 8; ++dt) {
                    const int d = d0w + dt * 16 + l15;
                    Bc[sb][dt].s = *(const u32x4*)(hTb + (size_t)d * 256
                                                   + (2 * ep + sb) * 32 + quad * 8);
                }
            #pragma unroll
            for (int sb = 0; sb < 2; ++sb) {
                const int et = 2 * ep + sb;
                Frag Ap[2];
                #pragma unroll
                for (int mt = 0; mt < 2; ++mt) {
                    const int ar = mt * 16 + l15;
                    Ap[mt].p.lo = *(const u32x2*)(Pt + ar * 260 + et * 32 + quad * 8);
                    Ap[mt].p.hi = *(const u32x2*)(Pt + ar * 260 + et * 32 + quad * 8 + 4);
                }
                #pragma unroll
                for (int dt = 0; dt < 8; ++dt)
                    #pragma unroll
                    for (int mt = 0; mt < 2; ++mt)
                        Uacc[mt * 8 + dt] = __builtin_amdgcn_mfma_f32_16x16x32_bf16(
                            Ap[mt].v, Bc[sb][dt].v, Uacc[mt * 8 + dt], 0, 0, 0);
            }
        }
    } else {
        // fallback: pair-packed in-LDS transpose from packed h (hi halves)
        u32* Hb32 = (u32*)HbT;
        for (int et = 0; et < 8; ++et) {
            {
                const int epi = lane & 15;
                const int q   = lane >> 4;
                const size_t r0p = hb_base + (size_t)(et * 32 + 2 * epi) * 1024;
                #pragma unroll
                for (int c = 0; c < 4; ++c) {
                    const int d0c = d0w + c * 32 + q * 8;
                    const size_t po = (size_t)(d0c >> 5) * 64 + (d0c & 31);
                    u32x4 u0 = *(const u32x4*)(h_p + r0p + po);
                    u32x4 u1 = *(const u32x4*)(h_p + r0p + 1024 + po);
                    #pragma unroll
                    for (int p = 0; p < 4; ++p) {
                        const u32 w0 = (u0[p] & 0xFFFFu) | (u1[p] << 16);
                        const u32 w1 = (u0[p] >> 16) | (u1[p] & 0xFFFF0000u);
                        Hb32[(d0c + 2 * p) * 18 + epi]     = w0;
                        Hb32[(d0c + 2 * p + 1) * 18 + epi] = w1;
                    }
                }
            }
            Frag Ap[2];
            #pragma unroll
            for (int mt = 0; mt < 2; ++mt) {
                const int ar = mt * 16 + l15;
                Ap[mt].p.lo = *(const u32x2*)(Pt + ar * 260 + et * 32 + quad * 8);
                Ap[mt].p.hi = *(const u32x2*)(Pt + ar * 260 + et * 32 + quad * 8 + 4);
            }
            #pragma unroll
            for (int dt = 0; dt < 8; ++dt) {
                const int d = d0w + dt * 16 + l15;
                Frag Bf;
                Bf.p.lo = *(const u32x2*)(HbT + d * 36 + quad * 8);
                Bf.p.hi = *(const u32x2*)(HbT + d * 36 + quad * 8 + 4);
                #pragma unroll
                for (int mt = 0; mt < 2; ++mt)
                    Uacc[mt * 8 + dt] = __builtin_amdgcn_mfma_f32_16x16x32_bf16(
                        Ap[mt].v, Bf.v, Uacc[mt * 8 + dt], 0, 0, 0);
            }
        }
    }
    __syncthreads();
    #pragma unroll
    for (int mt = 0; mt < 2; ++mt)
        #pragma unroll
        for (int dt = 0; dt < 8; ++dt)
            #pragma unroll
            for (int r = 0; r < 4; ++r) {
                const int a = mt * 16 + quad * 4 + r;
                const int d = d0w + dt * 16 + l15;
                U[a * 520 + d] = f2bf(Uacc[mt * 8 + dt][r]);
            }
    __syncthreads();
    // ---------- Phase D: z = U @ WVt, ks-paired (full-line consumption) ----------
    floatx4 Zacc[16];
    #pragma unroll
    for (int i = 0; i < 16; ++i) Zacc[i] = z4;
    for (int kp = 0; kp < 8; ++kp) {
        Frag Bw[2][8];
        #pragma unroll
        for (int sb = 0; sb < 2; ++sb) {
            const int k = (kp * 2 + sb) * 32 + quad * 8;
            #pragma unroll
            for (int dt = 0; dt < 8; ++dt) {
                const int dn = (wid * 8 + dt) * 16 + l15;
                Bw[sb][dt].s = *(const u32x4*)(Wv + (size_t)dn * HID + k);
            }
        }
        #pragma unroll
        for (int sb = 0; sb < 2; ++sb) {
            const int k = (kp * 2 + sb) * 32 + quad * 8;
            Frag Au[2];
            #pragma unroll
            for (int mt = 0; mt < 2; ++mt) {
                Au[mt].p.lo = *(const u32x2*)(U + (mt * 16 + l15) * 520 + k);
                Au[mt].p.hi = *(const u32x2*)(U + (mt * 16 + l15) * 520 + k + 4);
            }
            #pragma unroll
            for (int dt = 0; dt < 8; ++dt)
                #pragma unroll
                for (int mt = 0; mt < 2; ++mt)
                    Zacc[mt * 8 + dt] = __builtin_amdgcn_mfma_f32_16x16x32_bf16(
                        Au[mt].v, Bw[sb][dt].v, Zacc[mt * 8 + dt], 0, 0, 0);
        }
    }
    float* ob = out + ((size_t)b * NAGENT + at * 32) * HID;
    #pragma unroll
    for (int mt = 0; mt < 2; ++mt)
        #pragma unroll
        for (int dt = 0; dt < 8; ++dt)
            #pragma unroll
            for (int r = 0; r < 4; ++r) {
                const int a  = mt * 16 + quad * 4 + r;
                const int dn = (wid * 8 + dt) * 16 + l15;
                atomicAdd(ob + (size_t)a * HID + dn, Zacc[mt * 8 + dt][r] * 0.125f);
            }
}

// -----------------------------------------------------------------------------
// ws layout: h_p 64M [0,64M) | Mt_p 8M [64M,72M) | WVt 4M [72M,76M)
//            | hT 32M [76M,108M) (useHT iff ws >= 108 MB)
// Wt_p (512 KB) transiently lives at WVt start: wenc_t -> enc -> wvt overwrites.
// -----------------------------------------------------------------------------
extern "C" void kernel_launch(void* const* d_in, const int* in_sizes, int n_in,
                              void* d_out, int out_size, void* d_ws, size_t ws_size,
                              hipStream_t stream) {
    const float* x     = (const float*)d_in[0];
    const float* W_enc = (const float*)d_in[1];
    const float* b_enc = (const float*)d_in[2];
    const float* WQ    = (const float*)d_in[3];
    const float* WK    = (const float*)d_in[4];
    const float* WV    = (const float*)d_in[5];
    float* out = (float*)d_out;

    char* ws = (char*)d_ws;
    u16* h_p  = (u16*)ws;
    u16* Mt_p = (u16*)(ws + 67108864);
    u16* WVt  = (u16*)(ws + 75497472);
    u16* hT   = (u16*)(ws + 79691776);
    u16* Wt_p = WVt;                       // transient, 512 KB

    const bool useHT = ws_size >= (size_t)113246208;  // 108 MB

    hipMemsetAsync(d_out, 0, (size_t)out_size * sizeof(float), stream);
    wenc_t_kernel<<<32, 256, 0, stream>>>(W_enc, Wt_p);
    enc_kernel<<<1024, 256, 0, stream>>>(x, Wt_p, b_enc, h_p);
    if (useHT) ht_kernel<<<4096, 256, 0, stream>>>(h_p, hT);
    wvt_kernel<<<512, 256, 0, stream>>>(WV, WVt);
    wqk_kernel<<<512, 256, 0, stream>>>(WQ, WK, Mt_p);
    if (useHT)
        attn_kernel<true><<<2048, 256, 0, stream>>>(h_p, Mt_p, WVt, hT, out);
    else
        attn_kernel<false><<<2048, 256, 0, stream>>>(h_p, Mt_p, WVt, hT, out);
}